// Round 5
// baseline (216.312 us; speedup 1.0000x reference)
//
#include <hip/hip_runtime.h>

// VQ nearest-codebook, round 5: ZERO-barrier K-loop, explicit 2-deep register
// double-buffer of pre-swizzled B-fragments (per-wave global dwordx4, L2-hit),
// med3 second-min tracking, LDS-staged coalesced epilogue gather.
//
// x: (2, 40, 64, 1500) f32 ; cb: (40, 1024, 64) f32
// out[b,band,c,t] = cb[band, argmin_k ||x[b,band,:,t]-cb[band,k]||^2, c]

#define NBAND  40
#define CH     64
#define TT     1500
#define NCODE  1024
#define MT     128     // t-tile per block
#define PAD    68      // x staging row stride (ushorts)
#define THRESH 1e-3f   // rescue margin; bf16-split err bound ~2e-4

typedef short v8s __attribute__((ext_vector_type(8)));
typedef float v4f __attribute__((ext_vector_type(4)));

// ws: CBF fragments [band][group 0..31][plane 0..7][lane 0..63][8 ushorts]
//   plane = ni*2+ks (hi) / 4+ni*2+ks (lo); content = code g*32+ni*16+(lane&15),
//   c = ks*32+(lane>>4)*8 .. +8.  Then C2 float[40*1024].
#define CBF_USHORTS ((size_t)NBAND * 32 * 8 * 64 * 8)
#define CBF_BYTES   (CBF_USHORTS * 2)
#define WS_NEEDED   (CBF_BYTES + (size_t)NBAND * NCODE * 4)

__device__ __forceinline__ unsigned short f2bf(float f) {
    unsigned u = __float_as_uint(f);
    return (unsigned short)((u + 0x7FFFu + ((u >> 16) & 1u)) >> 16);   // RNE
}
__device__ __forceinline__ float bf2f(unsigned short h) {
    return __uint_as_float(((unsigned)h) << 16);
}
__device__ __forceinline__ unsigned ford(float f) {
    unsigned u = __float_as_uint(f);
    return (u & 0x80000000u) ? ~u : (u | 0x80000000u);
}
__device__ __forceinline__ unsigned long long packsk(float f, unsigned k) {
    return ((unsigned long long)ford(f) << 32) | (unsigned long long)k;
}
__device__ __forceinline__ float med3f(float a, float b, float c) {
#if __has_builtin(__builtin_amdgcn_fmed3f)
    return __builtin_amdgcn_fmed3f(a, b, c);
#else
    return fminf(fmaxf(a, b), c);
#endif
}

// ---------------- prep: split + swizzle codebook into ws ----------------
__global__ __launch_bounds__(256)
void vq_prep(const float* __restrict__ cb,
             unsigned short* __restrict__ CBF,
             float* __restrict__ C2) {
    const int band = blockIdx.y;
    const int g    = blockIdx.x * 4 + (threadIdx.x >> 6);   // grid.x = 8
    const int lane = threadIdx.x & 63;
    const int col  = lane & 15;
    const int quad = lane >> 4;

    float sq[2] = {0.f, 0.f};
    #pragma unroll
    for (int l = 0; l < 4; ++l) {
        const int ni = l >> 1, ks = l & 1;
        const int code = g * 32 + ni * 16 + col;
        const int c0   = ks * 32 + quad * 8;
        const float* src = cb + ((size_t)(band * NCODE + code)) * CH + c0;
        const float4 v0 = *(const float4*)src;
        const float4 v1 = *(const float4*)(src + 4);
        const float vv[8] = {v0.x, v0.y, v0.z, v0.w, v1.x, v1.y, v1.z, v1.w};
        union { unsigned short u[8]; v8s v; } hh, ll;
        #pragma unroll
        for (int j = 0; j < 8; ++j) {
            const unsigned short h = f2bf(vv[j]);
            hh.u[j] = h;
            ll.u[j] = f2bf(vv[j] - bf2f(h));
            sq[ni] = fmaf(vv[j], vv[j], sq[ni]);
        }
        const size_t gb = (size_t)(band * 32 + g) * 8;
        *(v8s*)&CBF[(gb + l)     * 512 + lane * 8] = hh.v;
        *(v8s*)&CBF[(gb + 4 + l) * 512 + lane * 8] = ll.v;
    }
    #pragma unroll
    for (int ni = 0; ni < 2; ++ni) {
        sq[ni] += __shfl_xor(sq[ni], 16);
        sq[ni] += __shfl_xor(sq[ni], 32);
    }
    if (quad == 0) {
        C2[band * NCODE + g * 32 + col]      = sq[0];
        C2[band * NCODE + g * 32 + 16 + col] = sq[1];
    }
}

// ---------------- main ----------------
__global__ __launch_bounds__(256, 3)
void vq_main(const float* __restrict__ x,
             const float* __restrict__ cb,
             const unsigned short* __restrict__ CBF,
             const float* __restrict__ C2f,
             float* __restrict__ out) {
    __shared__ alignas(16) unsigned char SMEM[MT * PAD * 2 * 2];   // 34816 B
    __shared__ float c2_s[NCODE];
    __shared__ unsigned long long best_s[MT];
    __shared__ unsigned amb_s[4];
    __shared__ float xrow_s[CH];

    unsigned short* XH_s = (unsigned short*)SMEM;
    unsigned short* XL_s = XH_s + MT * PAD;

    const int tile  = blockIdx.x;
    const int band  = blockIdx.y;
    const int batch = blockIdx.z;
    const int t0    = tile * MT;

    const int tid  = threadIdx.x;
    const int wave = tid >> 6;
    const int lane = tid & 63;
    const int quad = lane >> 4;
    const int col  = lane & 15;

    if (tid < 4) amb_s[tid] = 0u;
    {
        const float* src = C2f + band * NCODE;
        #pragma unroll
        for (int i = 0; i < 4; ++i) c2_s[tid + 256 * i] = src[tid + 256 * i];
    }
    // stage x tile as bf16 hi/lo, [t][c] padded rows
    {
        const int c = tid & 63;
        const int g = tid >> 6;
        const float* src = x + ((size_t)(batch * NBAND + band) * CH + c) * TT + t0;
        #pragma unroll
        for (int i = 0; i < 8; ++i) {
            const int t = (g + 4 * i) * 4;
            float4 v = make_float4(0.f, 0.f, 0.f, 0.f);
            if (t0 + t + 3 < TT) v = *(const float4*)(src + t);   // TT%4==0
            const float vv[4] = {v.x, v.y, v.z, v.w};
            #pragma unroll
            for (int j = 0; j < 4; ++j) {
                const unsigned short h = f2bf(vv[j]);
                XH_s[(t + j) * PAD + c] = h;
                XL_s[(t + j) * PAD + c] = f2bf(vv[j] - bf2f(h));
            }
        }
    }
    __syncthreads();

    // A fragments register-resident: A[m=lane&15][k=quad*8+j], +16*mi rows, +32*ks k
    v8s ah[2][2], al[2][2];
    #pragma unroll
    for (int mi = 0; mi < 2; ++mi)
        #pragma unroll
        for (int ks = 0; ks < 2; ++ks) {
            const int off = (wave * 32 + mi * 16 + col) * PAD + ks * 32 + quad * 8;
            ah[mi][ks] = *(const v8s*)&XH_s[off];
            al[mi][ks] = *(const v8s*)&XL_s[off];
        }
    __syncthreads();   // x-tile consumed; SMEM reusable later

    float m1[8], m2[8];
    int   id8[8];
    #pragma unroll
    for (int i = 0; i < 8; ++i) { m1[i] = 3.4028235e38f; m2[i] = 3.4028235e38f; id8[i] = 0x7fffffff; }

    const unsigned short* fb = CBF + (size_t)(band * 32) * 4096 + (size_t)lane * 8;

    auto compute = [&](const v8s (&buf)[8], int g) {
        v4f acc[2][2];
        #pragma unroll
        for (int mi = 0; mi < 2; ++mi)
            #pragma unroll
            for (int ni = 0; ni < 2; ++ni) acc[mi][ni] = (v4f){0.f, 0.f, 0.f, 0.f};
        #pragma unroll
        for (int ks = 0; ks < 2; ++ks) {
            const v8s bh0 = buf[0 * 2 + ks], bh1 = buf[2 + ks];
            const v8s bl0 = buf[4 + ks],     bl1 = buf[6 + ks];
            #pragma unroll
            for (int mi = 0; mi < 2; ++mi) {
                acc[mi][0] = __builtin_amdgcn_mfma_f32_16x16x32_bf16(ah[mi][ks], bh0, acc[mi][0], 0, 0, 0);
                acc[mi][1] = __builtin_amdgcn_mfma_f32_16x16x32_bf16(ah[mi][ks], bh1, acc[mi][1], 0, 0, 0);
            }
            #pragma unroll
            for (int mi = 0; mi < 2; ++mi) {
                acc[mi][0] = __builtin_amdgcn_mfma_f32_16x16x32_bf16(ah[mi][ks], bl0, acc[mi][0], 0, 0, 0);
                acc[mi][1] = __builtin_amdgcn_mfma_f32_16x16x32_bf16(ah[mi][ks], bl1, acc[mi][1], 0, 0, 0);
            }
            #pragma unroll
            for (int mi = 0; mi < 2; ++mi) {
                acc[mi][0] = __builtin_amdgcn_mfma_f32_16x16x32_bf16(al[mi][ks], bh0, acc[mi][0], 0, 0, 0);
                acc[mi][1] = __builtin_amdgcn_mfma_f32_16x16x32_bf16(al[mi][ks], bh1, acc[mi][1], 0, 0, 0);
            }
        }
        // (m1, idx, m2): k strictly ascending per slot -> strict '<' keeps first-min
        #pragma unroll
        for (int ni = 0; ni < 2; ++ni) {
            const float c2v = c2_s[g * 32 + ni * 16 + col];
            const int   kg  = g * 32 + ni * 16 + col;
            #pragma unroll
            for (int mi = 0; mi < 2; ++mi)
                #pragma unroll
                for (int r = 0; r < 4; ++r) {
                    const int j = mi * 4 + r;
                    const float s = fmaf(-2.f, acc[mi][ni][r], c2v);
                    m2[j] = med3f(s, m1[j], m2[j]);   // = new second-min (m1<=m2 invariant)
                    const bool lt = s < m1[j];
                    m1[j]  = lt ? s : m1[j];
                    id8[j] = lt ? kg : id8[j];
                }
        }
    };

    // zero-barrier K-loop, 2-deep register double-buffer
    v8s bufA[8], bufB[8];
    #pragma unroll
    for (int p = 0; p < 8; ++p) bufA[p] = *(const v8s*)(fb + p * 512);

    for (int g = 0; g < 32; g += 2) {
        const unsigned short* nf = fb + (size_t)(g + 1) * 4096;
        #pragma unroll
        for (int p = 0; p < 8; ++p) bufB[p] = *(const v8s*)(nf + p * 512);
        compute(bufA, g);
        if (g + 2 < 32) {
            const unsigned short* nf2 = fb + (size_t)(g + 2) * 4096;
            #pragma unroll
            for (int p = 0; p < 8; ++p) bufA[p] = *(const v8s*)(nf2 + p * 512);
        }
        compute(bufB, g + 1);
    }
    __syncthreads();

    // cross-col reduction (alias SMEM)
    float* RM1 = (float*)SMEM;            // [MT][16]
    float* RM2 = RM1 + MT * 16;
    int*   RI  = (int*)(RM2 + MT * 16);
    #pragma unroll
    for (int j = 0; j < 8; ++j) {
        const int t = wave * 32 + (j >> 2) * 16 + quad * 4 + (j & 3);
        RM1[t * 16 + col] = m1[j];
        RM2[t * 16 + col] = m2[j];
        RI [t * 16 + col] = id8[j];
    }
    __syncthreads();

    if (tid < MT) {
        const int t = tid;
        float M1 = RM1[t * 16], M2 = RM2[t * 16];
        int   I  = RI[t * 16];
        #pragma unroll
        for (int j = 1; j < 16; ++j) {
            const float a1 = RM1[t * 16 + j];
            const float a2 = RM2[t * 16 + j];
            const int   ai = RI [t * 16 + j];
            if (a1 < M1 || (a1 == M1 && ai < I)) { M2 = fminf(M2, M1); M1 = a1; I = ai; }
            else                                  { M2 = fminf(M2, a1); }
            M2 = fminf(M2, a2);
        }
        best_s[t] = packsk(M1, (unsigned)I);
        if ((M2 - M1) <= THRESH && t0 + t < TT)
            atomicOr(&amb_s[t >> 5], 1u << (t & 31));
    }
    __syncthreads();

    // exact fp32 rescue for near-ties (rare)
    for (int t = 0; t < MT; ++t) {
        if ((amb_s[t >> 5] >> (t & 31)) & 1u) {
            if (tid < CH) xrow_s[tid] = x[((size_t)(batch * NBAND + band) * CH + tid) * TT + t0 + t];
            if (tid == CH) best_s[t] = ~0ULL;
            __syncthreads();
            #pragma unroll
            for (int i = 0; i < 4; ++i) {
                const int k = tid * 4 + i;
                const float* crow = cb + ((size_t)(band * NCODE + k)) * CH;
                float dot = 0.f, c2e = 0.f;
                #pragma unroll 8
                for (int c = 0; c < CH; ++c) {
                    const float cv = crow[c];
                    dot = fmaf(cv, xrow_s[c], dot);
                    c2e = fmaf(cv, cv, c2e);
                }
                atomicMin(&best_s[t], packsk(fmaf(-2.f, dot, c2e), (unsigned)k));
            }
            __syncthreads();
        }
    }
    __syncthreads();

    // epilogue via LDS: rows read coalesced (256B), stores coalesced along t
    {
        float* OT = (float*)SMEM;   // [MT][67] = 34304 B
        #pragma unroll
        for (int r = 0; r < MT; r += 4) {
            const int row = r + wave;
            const unsigned idx = (unsigned)(best_s[row] & 0xFFFFFFFFull) & (NCODE - 1);
            OT[row * 67 + lane] = cb[((size_t)(band * NCODE + idx)) * CH + lane];
        }
        __syncthreads();
        const int tloc  = tid & 127;
        const int chalf = tid >> 7;
        if (t0 + tloc < TT) {
            float* ob = out + ((size_t)(batch * NBAND + band) * CH) * TT + t0 + tloc;
            #pragma unroll
            for (int i = 0; i < 32; ++i) {
                const int c = chalf * 32 + i;
                ob[(size_t)c * TT] = OT[tloc * 67 + c];
            }
        }
    }
}

// ---------------- fallback: round-1 fp32 kernel (proven, ~290 us) ----------------
#define TN 128
#define KC 128
__global__ __launch_bounds__(256, 2)
void vq_fp32_kernel(const float* __restrict__ x,
                    const float* __restrict__ cb,
                    float* __restrict__ out) {
    __shared__ float XT_s[CH * TN];
    __shared__ float CBT_s[CH * KC];
    __shared__ float c2part[256];
    const int tile = blockIdx.x, band = blockIdx.y, batch = blockIdx.z;
    const int t0 = tile * TN;
    const int tid = threadIdx.x;
    const int tx = tid & 15, ty = tid >> 4;
    {
        const int c = tid >> 2, q = tid & 3;
        const float* src = x + ((size_t)(batch * NBAND + band) * CH + c) * TT + t0;
        #pragma unroll
        for (int i = 0; i < 8; ++i) {
            const int t = q * 32 + i * 4;
            float4 v = make_float4(0.f, 0.f, 0.f, 0.f);
            if (t0 + t < TT) v = *(const float4*)(src + t);
            *(float4*)&XT_s[c * TN + t] = v;
        }
    }
    float vmin[8]; int vidx[8];
    #pragma unroll
    for (int i = 0; i < 8; ++i) { vmin[i] = 3.4e38f; vidx[i] = 0x7fffffff; }
    for (int kc = 0; kc < NCODE; kc += KC) {
        __syncthreads();
        {
            const int k = tid >> 1, ch0 = (tid & 1) * 32;
            const float* src = cb + ((size_t)(band * NCODE + kc + k)) * CH + ch0;
            float s = 0.f;
            #pragma unroll
            for (int i = 0; i < 8; ++i) {
                const float4 v = *(const float4*)(src + i * 4);
                const int c0 = ch0 + i * 4;
                CBT_s[(c0 + 0) * KC + k] = v.x; CBT_s[(c0 + 1) * KC + k] = v.y;
                CBT_s[(c0 + 2) * KC + k] = v.z; CBT_s[(c0 + 3) * KC + k] = v.w;
                s = fmaf(v.x, v.x, s); s = fmaf(v.y, v.y, s);
                s = fmaf(v.z, v.z, s); s = fmaf(v.w, v.w, s);
            }
            c2part[tid] = s;
        }
        __syncthreads();
        float acc[8][8];
        #pragma unroll
        for (int ii = 0; ii < 8; ++ii)
            #pragma unroll
            for (int jj = 0; jj < 8; ++jj) acc[ii][jj] = 0.f;
        #pragma unroll 4
        for (int c = 0; c < CH; ++c) {
            const float4 xa0 = *(const float4*)&XT_s[c * TN + tx * 4];
            const float4 xa1 = *(const float4*)&XT_s[c * TN + 64 + tx * 4];
            const float4 cv0 = *(const float4*)&CBT_s[c * KC + ty * 4];
            const float4 cv1 = *(const float4*)&CBT_s[c * KC + 64 + ty * 4];
            const float xa[8] = {xa0.x, xa0.y, xa0.z, xa0.w, xa1.x, xa1.y, xa1.z, xa1.w};
            const float cv[8] = {cv0.x, cv0.y, cv0.z, cv0.w, cv1.x, cv1.y, cv1.z, cv1.w};
            #pragma unroll
            for (int ii = 0; ii < 8; ++ii)
                #pragma unroll
                for (int jj = 0; jj < 8; ++jj) acc[ii][jj] = fmaf(xa[ii], cv[jj], acc[ii][jj]);
        }
        #pragma unroll
        for (int jj = 0; jj < 8; ++jj) {
            const int kl = (jj < 4) ? (ty * 4 + jj) : (64 + ty * 4 + (jj - 4));
            const float c2v = c2part[2 * kl] + c2part[2 * kl + 1];
            const int kglob = kc + kl;
            #pragma unroll
            for (int ii = 0; ii < 8; ++ii) {
                const float score = fmaf(-2.f, acc[ii][jj], c2v);
                if (score < vmin[ii]) { vmin[ii] = score; vidx[ii] = kglob; }
            }
        }
    }
    __syncthreads();
    float* redv = XT_s;
    int* redi = (int*)(XT_s + TN * 16);
    int* idxs = (int*)(XT_s + TN * 32);
    #pragma unroll
    for (int ii = 0; ii < 8; ++ii) {
        const int t = (ii < 4) ? (tx * 4 + ii) : (64 + tx * 4 + (ii - 4));
        redv[t * 16 + ty] = vmin[ii];
        redi[t * 16 + ty] = vidx[ii];
    }
    __syncthreads();
    if (tid < TN) {
        float bv = redv[tid * 16]; int bi = redi[tid * 16];
        #pragma unroll
        for (int j = 1; j < 16; ++j) {
            const float v = redv[tid * 16 + j]; const int id = redi[tid * 16 + j];
            if (v < bv || (v == bv && id < bi)) { bv = v; bi = id; }
        }
        idxs[tid] = bi;
    }
    __syncthreads();
    {
        const int tloc = tid & 127, chalf = tid >> 7;
        if (t0 + tloc < TT) {
            const int idx = idxs[tloc];
            const float* crow = cb + ((size_t)(band * NCODE + idx)) * CH;
            float* ob = out + ((size_t)(batch * NBAND + band) * CH) * TT + t0 + tloc;
            #pragma unroll
            for (int i = 0; i < 32; ++i) {
                const int c = chalf * 32 + i;
                ob[(size_t)c * TT] = crow[c];
            }
        }
    }
}

extern "C" void kernel_launch(void* const* d_in, const int* in_sizes, int n_in,
                              void* d_out, int out_size, void* d_ws, size_t ws_size,
                              hipStream_t stream) {
    const float* x  = (const float*)d_in[0];
    const float* cb = (const float*)d_in[1];
    float* out = (float*)d_out;
    dim3 grid((TT + MT - 1) / MT, NBAND, 2);
    if (ws_size >= WS_NEEDED) {
        unsigned short* CBF = (unsigned short*)d_ws;
        float* C2 = (float*)((char*)d_ws + CBF_BYTES);
        vq_prep<<<dim3(8, NBAND), dim3(256), 0, stream>>>(cb, CBF, C2);
        vq_main<<<grid, dim3(256), 0, stream>>>(x, cb, CBF, C2, out);
    } else {
        vq_fp32_kernel<<<grid, dim3(256), 0, stream>>>(x, cb, out);
    }
}

// Round 6
// 205.401 us; speedup vs baseline: 1.0531x; 1.0531x over previous
//
#include <hip/hip_runtime.h>

// VQ nearest-codebook, round 6: CONCURRENCY fix.
// 1920 blocks (MT=64), 4 waves = (t-half x k-half) split, LDS-shared async
// fragment staging (global_load_lds, 2 groups/round, double-buffered),
// 4 blocks/CU resident, 7.5 blocks/CU total -> block-level pipelining.
//
// x: (2, 40, 64, 1500) f32 ; cb: (40, 1024, 64) f32
// out[b,band,c,t] = cb[band, argmin_k ||x[b,band,:,t]-cb[band,k]||^2, c]

#define NBAND  40
#define CH     64
#define TT     1500
#define NCODE  1024
#define MT     64      // t-tile per block
#define PAD    68      // x staging row stride (ushorts)
#define THRESH 1e-3f   // rescue margin; bf16-split err bound ~2e-4

typedef short v8s __attribute__((ext_vector_type(8)));
typedef float v4f __attribute__((ext_vector_type(4)));

// ws: CBF fragments [band][group 0..31][plane 0..7][lane 0..63][8 ushorts]
//   plane = ni*2+ks (hi) / 4+ni*2+ks (lo); content = code g*32+ni*16+(lane&15),
//   c = ks*32+(lane>>4)*8 .. +8.  Then C2 float[40*1024].
#define CBF_USHORTS ((size_t)NBAND * 32 * 8 * 64 * 8)
#define CBF_BYTES   (CBF_USHORTS * 2)
#define WS_NEEDED   (CBF_BYTES + (size_t)NBAND * NCODE * 4)

__device__ __forceinline__ unsigned short f2bf(float f) {
    unsigned u = __float_as_uint(f);
    return (unsigned short)((u + 0x7FFFu + ((u >> 16) & 1u)) >> 16);   // RNE
}
__device__ __forceinline__ float bf2f(unsigned short h) {
    return __uint_as_float(((unsigned)h) << 16);
}
__device__ __forceinline__ unsigned ford(float f) {
    unsigned u = __float_as_uint(f);
    return (u & 0x80000000u) ? ~u : (u | 0x80000000u);
}
__device__ __forceinline__ unsigned long long packsk(float f, unsigned k) {
    return ((unsigned long long)ford(f) << 32) | (unsigned long long)k;
}
__device__ __forceinline__ float med3f(float a, float b, float c) {
#if __has_builtin(__builtin_amdgcn_fmed3f)
    return __builtin_amdgcn_fmed3f(a, b, c);
#else
    return fminf(fmaxf(a, b), c);
#endif
}

typedef __attribute__((address_space(1))) const unsigned char* gas_p;
typedef __attribute__((address_space(3))) unsigned char*       las_p;
__device__ __forceinline__ void async_ld16(const void* g, void* l) {
    __builtin_amdgcn_global_load_lds((gas_p)g, (las_p)l, 16, 0, 0);
}

// ---------------- prep: split + swizzle codebook into ws ----------------
__global__ __launch_bounds__(256)
void vq_prep(const float* __restrict__ cb,
             unsigned short* __restrict__ CBF,
             float* __restrict__ C2) {
    const int band = blockIdx.y;
    const int g    = blockIdx.x * 4 + (threadIdx.x >> 6);   // grid.x = 8
    const int lane = threadIdx.x & 63;
    const int col  = lane & 15;
    const int quad = lane >> 4;

    float sq[2] = {0.f, 0.f};
    #pragma unroll
    for (int l = 0; l < 4; ++l) {
        const int ni = l >> 1, ks = l & 1;
        const int code = g * 32 + ni * 16 + col;
        const int c0   = ks * 32 + quad * 8;
        const float* src = cb + ((size_t)(band * NCODE + code)) * CH + c0;
        const float4 v0 = *(const float4*)src;
        const float4 v1 = *(const float4*)(src + 4);
        const float vv[8] = {v0.x, v0.y, v0.z, v0.w, v1.x, v1.y, v1.z, v1.w};
        union { unsigned short u[8]; v8s v; } hh, ll;
        #pragma unroll
        for (int j = 0; j < 8; ++j) {
            const unsigned short h = f2bf(vv[j]);
            hh.u[j] = h;
            ll.u[j] = f2bf(vv[j] - bf2f(h));
            sq[ni] = fmaf(vv[j], vv[j], sq[ni]);
        }
        const size_t gb = (size_t)(band * 32 + g) * 8;
        *(v8s*)&CBF[(gb + l)     * 512 + lane * 8] = hh.v;
        *(v8s*)&CBF[(gb + 4 + l) * 512 + lane * 8] = ll.v;
    }
    #pragma unroll
    for (int ni = 0; ni < 2; ++ni) {
        sq[ni] += __shfl_xor(sq[ni], 16);
        sq[ni] += __shfl_xor(sq[ni], 32);
    }
    if (quad == 0) {
        C2[band * NCODE + g * 32 + col]      = sq[0];
        C2[band * NCODE + g * 32 + 16 + col] = sq[1];
    }
}

// ---------------- main ----------------
__global__ __launch_bounds__(256, 4)
void vq_main(const float* __restrict__ x,
             const float* __restrict__ cb,
             const unsigned short* __restrict__ CBF,
             const float* __restrict__ C2f,
             float* __restrict__ out) {
    // 32 KB region: [x-stage hi/lo 17.4K] -> [frag dbuf 2x16K] -> [reduce 24K / epi 17.2K]
    __shared__ alignas(16) unsigned char SMEM[32768];
    __shared__ float c2_s[NCODE];                 // 4 KB
    __shared__ unsigned long long best_s[MT];     // 512 B
    __shared__ unsigned amb_s[2];
    __shared__ float xrow_s[CH];

    const int tile  = blockIdx.x;
    const int band  = blockIdx.y;
    const int batch = blockIdx.z;
    const int t0    = tile * MT;

    const int tid   = threadIdx.x;
    const int wave  = tid >> 6;
    const int lane  = tid & 63;
    const int quad  = lane >> 4;
    const int col   = lane & 15;
    const int thalf = wave & 1;    // t rows [32*thalf, +32)
    const int khalf = wave >> 1;   // codes [512*khalf, +512)

    if (tid < 2) amb_s[tid] = 0u;
    {
        const float* src = C2f + band * NCODE;
        #pragma unroll
        for (int i = 0; i < 4; ++i) c2_s[tid + 256 * i] = src[tid + 256 * i];
    }
    // stage x tile as bf16 hi/lo, [t][c] padded rows (MT=64)
    {
        unsigned short* XH_s = (unsigned short*)SMEM;
        unsigned short* XL_s = XH_s + MT * PAD;
        const int c = tid & 63;
        const int g = tid >> 6;
        const float* src = x + ((size_t)(batch * NBAND + band) * CH + c) * TT + t0;
        #pragma unroll
        for (int i = 0; i < 4; ++i) {
            const int t = (g + 4 * i) * 4;
            float4 v = make_float4(0.f, 0.f, 0.f, 0.f);
            if (t0 + t + 3 < TT) v = *(const float4*)(src + t);   // TT%4==0
            const float vv[4] = {v.x, v.y, v.z, v.w};
            #pragma unroll
            for (int j = 0; j < 4; ++j) {
                const unsigned short h = f2bf(vv[j]);
                XH_s[(t + j) * PAD + c] = h;
                XL_s[(t + j) * PAD + c] = f2bf(vv[j] - bf2f(h));
            }
        }
    }
    __syncthreads();

    // A fragments register-resident: rows 32*thalf + mi*16 + col
    v8s ah[2][2], al[2][2];
    {
        unsigned short* XH_s = (unsigned short*)SMEM;
        unsigned short* XL_s = XH_s + MT * PAD;
        #pragma unroll
        for (int mi = 0; mi < 2; ++mi)
            #pragma unroll
            for (int ks = 0; ks < 2; ++ks) {
                const int off = (thalf * 32 + mi * 16 + col) * PAD + ks * 32 + quad * 8;
                ah[mi][ks] = *(const v8s*)&XH_s[off];
                al[mi][ks] = *(const v8s*)&XL_s[off];
            }
    }
    __syncthreads();   // x-tile consumed; SMEM becomes the fragment double-buffer

    float m1[8], m2[8];
    int   id8[8];
    #pragma unroll
    for (int i = 0; i < 8; ++i) { m1[i] = 3.4028235e38f; m2[i] = 3.4028235e38f; id8[i] = 0x7fffffff; }

    // staging: wave w stages 4 planes of its k-half's group for round r
    unsigned short* LBUF = (unsigned short*)SMEM;                 // [2][2][8][512]
    const unsigned short* cbase = CBF + (size_t)(band * 32) * 4096 + (size_t)lane * 8;
    const int pbase = (thalf) * 4;   // local planes staged by this wave

    auto stage_round = [&](int r, int b) {
        const int group = khalf * 16 + r;
        #pragma unroll
        for (int i = 0; i < 4; ++i) {
            const int p = pbase + i;
            async_ld16(cbase + (size_t)group * 4096 + p * 512,
                       LBUF + (size_t)b * 8192 + khalf * 4096 + p * 512);  // HW adds lane*16B
        }
    };

    stage_round(0, 0);

    for (int r = 0; r < 16; ++r) {
        __syncthreads();                       // own async loads drained -> buf[r&1] complete
        if (r + 1 < 16) stage_round(r + 1, (r + 1) & 1);

        const unsigned short* lb = LBUF + (size_t)(r & 1) * 8192 + khalf * 4096 + lane * 8;
        v4f acc[2][2];
        #pragma unroll
        for (int mi = 0; mi < 2; ++mi)
            #pragma unroll
            for (int ni = 0; ni < 2; ++ni) acc[mi][ni] = (v4f){0.f, 0.f, 0.f, 0.f};

        #pragma unroll
        for (int ks = 0; ks < 2; ++ks) {
            const v8s bh0 = *(const v8s*)(lb + (0 + ks) * 512);
            const v8s bh1 = *(const v8s*)(lb + (2 + ks) * 512);
            const v8s bl0 = *(const v8s*)(lb + (4 + ks) * 512);
            const v8s bl1 = *(const v8s*)(lb + (6 + ks) * 512);
            #pragma unroll
            for (int mi = 0; mi < 2; ++mi) {
                acc[mi][0] = __builtin_amdgcn_mfma_f32_16x16x32_bf16(ah[mi][ks], bh0, acc[mi][0], 0, 0, 0);
                acc[mi][1] = __builtin_amdgcn_mfma_f32_16x16x32_bf16(ah[mi][ks], bh1, acc[mi][1], 0, 0, 0);
            }
            #pragma unroll
            for (int mi = 0; mi < 2; ++mi) {
                acc[mi][0] = __builtin_amdgcn_mfma_f32_16x16x32_bf16(ah[mi][ks], bl0, acc[mi][0], 0, 0, 0);
                acc[mi][1] = __builtin_amdgcn_mfma_f32_16x16x32_bf16(ah[mi][ks], bl1, acc[mi][1], 0, 0, 0);
            }
            #pragma unroll
            for (int mi = 0; mi < 2; ++mi) {
                acc[mi][0] = __builtin_amdgcn_mfma_f32_16x16x32_bf16(al[mi][ks], bh0, acc[mi][0], 0, 0, 0);
                acc[mi][1] = __builtin_amdgcn_mfma_f32_16x16x32_bf16(al[mi][ks], bh1, acc[mi][1], 0, 0, 0);
            }
        }
        // (m1, idx, m2): k strictly ascending per slot -> strict '<' keeps first-min
        #pragma unroll
        for (int ni = 0; ni < 2; ++ni) {
            const int   kg  = khalf * 512 + r * 32 + ni * 16 + col;
            const float c2v = c2_s[kg];
            #pragma unroll
            for (int mi = 0; mi < 2; ++mi)
                #pragma unroll
                for (int rr = 0; rr < 4; ++rr) {
                    const int j = mi * 4 + rr;
                    const float s = fmaf(-2.f, acc[mi][ni][rr], c2v);
                    m2[j] = med3f(s, m1[j], m2[j]);   // new second-min (m1<=m2 invariant)
                    const bool lt = s < m1[j];
                    m1[j]  = lt ? s : m1[j];
                    id8[j] = lt ? kg : id8[j];
                }
        }
    }
    __syncthreads();

    // cross-(col,khalf) reduction: 32 partials per t (alias SMEM)
    float* RM1 = (float*)SMEM;            // [MT][32]
    float* RM2 = RM1 + MT * 32;           // [MT][32]
    int*   RI  = (int*)(RM2 + MT * 32);   // [MT][32]
    #pragma unroll
    for (int j = 0; j < 8; ++j) {
        const int t    = thalf * 32 + (j >> 2) * 16 + quad * 4 + (j & 3);
        const int slot = khalf * 16 + col;
        RM1[t * 32 + slot] = m1[j];
        RM2[t * 32 + slot] = m2[j];
        RI [t * 32 + slot] = id8[j];
    }
    __syncthreads();

    if (tid < MT) {
        const int t = tid;
        float M1 = RM1[t * 32], M2 = RM2[t * 32];
        int   I  = RI[t * 32];
        #pragma unroll 8
        for (int j = 1; j < 32; ++j) {
            const float a1 = RM1[t * 32 + j];
            const float a2 = RM2[t * 32 + j];
            const int   ai = RI [t * 32 + j];
            if (a1 < M1 || (a1 == M1 && ai < I)) { M2 = fminf(M2, M1); M1 = a1; I = ai; }
            else                                  { M2 = fminf(M2, a1); }
            M2 = fminf(M2, a2);
        }
        best_s[t] = packsk(M1, (unsigned)I);
        if ((M2 - M1) <= THRESH && t0 + t < TT)
            atomicOr(&amb_s[t >> 5], 1u << (t & 31));
    }
    __syncthreads();

    // exact fp32 rescue for near-ties (rare)
    for (int t = 0; t < MT; ++t) {
        if ((amb_s[t >> 5] >> (t & 31)) & 1u) {
            if (tid < CH) xrow_s[tid] = x[((size_t)(batch * NBAND + band) * CH + tid) * TT + t0 + t];
            if (tid == CH) best_s[t] = ~0ULL;
            __syncthreads();
            #pragma unroll
            for (int i = 0; i < 4; ++i) {
                const int k = tid * 4 + i;
                const float* crow = cb + ((size_t)(band * NCODE + k)) * CH;
                float dot = 0.f, c2e = 0.f;
                #pragma unroll 8
                for (int c = 0; c < CH; ++c) {
                    const float cv = crow[c];
                    dot = fmaf(cv, xrow_s[c], dot);
                    c2e = fmaf(cv, cv, c2e);
                }
                atomicMin(&best_s[t], packsk(fmaf(-2.f, dot, c2e), (unsigned)k));
            }
            __syncthreads();
        }
    }
    __syncthreads();

    // epilogue via LDS: rows read coalesced (256B), stores coalesced along t
    {
        float* OT = (float*)SMEM;   // [MT][67] = 17152 B
        #pragma unroll
        for (int rr = 0; rr < MT; rr += 4) {
            const int row = rr + wave;
            const unsigned idx = (unsigned)(best_s[row] & 0xFFFFFFFFull) & (NCODE - 1);
            OT[row * 67 + lane] = cb[((size_t)(band * NCODE + idx)) * CH + lane];
        }
        __syncthreads();
        const int tloc = tid & 63;
        const int cq   = tid >> 6;   // 0..3
        if (t0 + tloc < TT) {
            float* ob = out + ((size_t)(batch * NBAND + band) * CH) * TT + t0 + tloc;
            #pragma unroll
            for (int i = 0; i < 16; ++i) {
                const int c = cq * 16 + i;
                ob[(size_t)c * TT] = OT[tloc * 67 + c];
            }
        }
    }
}

// ---------------- fallback: round-1 fp32 kernel (proven, ~290 us) ----------------
#define TN 128
#define KC 128
__global__ __launch_bounds__(256, 2)
void vq_fp32_kernel(const float* __restrict__ x,
                    const float* __restrict__ cb,
                    float* __restrict__ out) {
    __shared__ float XT_s[CH * TN];
    __shared__ float CBT_s[CH * KC];
    __shared__ float c2part[256];
    const int tile = blockIdx.x, band = blockIdx.y, batch = blockIdx.z;
    const int t0 = tile * TN;
    const int tid = threadIdx.x;
    const int tx = tid & 15, ty = tid >> 4;
    {
        const int c = tid >> 2, q = tid & 3;
        const float* src = x + ((size_t)(batch * NBAND + band) * CH + c) * TT + t0;
        #pragma unroll
        for (int i = 0; i < 8; ++i) {
            const int t = q * 32 + i * 4;
            float4 v = make_float4(0.f, 0.f, 0.f, 0.f);
            if (t0 + t < TT) v = *(const float4*)(src + t);
            *(float4*)&XT_s[c * TN + t] = v;
        }
    }
    float vmin[8]; int vidx[8];
    #pragma unroll
    for (int i = 0; i < 8; ++i) { vmin[i] = 3.4e38f; vidx[i] = 0x7fffffff; }
    for (int kc = 0; kc < NCODE; kc += KC) {
        __syncthreads();
        {
            const int k = tid >> 1, ch0 = (tid & 1) * 32;
            const float* src = cb + ((size_t)(band * NCODE + kc + k)) * CH + ch0;
            float s = 0.f;
            #pragma unroll
            for (int i = 0; i < 8; ++i) {
                const float4 v = *(const float4*)(src + i * 4);
                const int c0 = ch0 + i * 4;
                CBT_s[(c0 + 0) * KC + k] = v.x; CBT_s[(c0 + 1) * KC + k] = v.y;
                CBT_s[(c0 + 2) * KC + k] = v.z; CBT_s[(c0 + 3) * KC + k] = v.w;
                s = fmaf(v.x, v.x, s); s = fmaf(v.y, v.y, s);
                s = fmaf(v.z, v.z, s); s = fmaf(v.w, v.w, s);
            }
            c2part[tid] = s;
        }
        __syncthreads();
        float acc[8][8];
        #pragma unroll
        for (int ii = 0; ii < 8; ++ii)
            #pragma unroll
            for (int jj = 0; jj < 8; ++jj) acc[ii][jj] = 0.f;
        #pragma unroll 4
        for (int c = 0; c < CH; ++c) {
            const float4 xa0 = *(const float4*)&XT_s[c * TN + tx * 4];
            const float4 xa1 = *(const float4*)&XT_s[c * TN + 64 + tx * 4];
            const float4 cv0 = *(const float4*)&CBT_s[c * KC + ty * 4];
            const float4 cv1 = *(const float4*)&CBT_s[c * KC + 64 + ty * 4];
            const float xa[8] = {xa0.x, xa0.y, xa0.z, xa0.w, xa1.x, xa1.y, xa1.z, xa1.w};
            const float cv[8] = {cv0.x, cv0.y, cv0.z, cv0.w, cv1.x, cv1.y, cv1.z, cv1.w};
            #pragma unroll
            for (int ii = 0; ii < 8; ++ii)
                #pragma unroll
                for (int jj = 0; jj < 8; ++jj) acc[ii][jj] = fmaf(xa[ii], cv[jj], acc[ii][jj]);
        }
        #pragma unroll
        for (int jj = 0; jj < 8; ++jj) {
            const int kl = (jj < 4) ? (ty * 4 + jj) : (64 + ty * 4 + (jj - 4));
            const float c2v = c2part[2 * kl] + c2part[2 * kl + 1];
            const int kglob = kc + kl;
            #pragma unroll
            for (int ii = 0; ii < 8; ++ii) {
                const float score = fmaf(-2.f, acc[ii][jj], c2v);
                if (score < vmin[ii]) { vmin[ii] = score; vidx[ii] = kglob; }
            }
        }
    }
    __syncthreads();
    float* redv = XT_s;
    int* redi = (int*)(XT_s + TN * 16);
    int* idxs = (int*)(XT_s + TN * 32);
    #pragma unroll
    for (int ii = 0; ii < 8; ++ii) {
        const int t = (ii < 4) ? (tx * 4 + ii) : (64 + tx * 4 + (ii - 4));
        redv[t * 16 + ty] = vmin[ii];
        redi[t * 16 + ty] = vidx[ii];
    }
    __syncthreads();
    if (tid < TN) {
        float bv = redv[tid * 16]; int bi = redi[tid * 16];
        #pragma unroll
        for (int j = 1; j < 16; ++j) {
            const float v = redv[tid * 16 + j]; const int id = redi[tid * 16 + j];
            if (v < bv || (v == bv && id < bi)) { bv = v; bi = id; }
        }
        idxs[tid] = bi;
    }
    __syncthreads();
    {
        const int tloc = tid & 127, chalf = tid >> 7;
        if (t0 + tloc < TT) {
            const int idx = idxs[tloc];
            const float* crow = cb + ((size_t)(band * NCODE + idx)) * CH;
            float* ob = out + ((size_t)(batch * NBAND + band) * CH) * TT + t0 + tloc;
            #pragma unroll
            for (int i = 0; i < 32; ++i) {
                const int c = chalf * 32 + i;
                ob[(size_t)c * TT] = crow[c];
            }
        }
    }
}

extern "C" void kernel_launch(void* const* d_in, const int* in_sizes, int n_in,
                              void* d_out, int out_size, void* d_ws, size_t ws_size,
                              hipStream_t stream) {
    const float* x  = (const float*)d_in[0];
    const float* cb = (const float*)d_in[1];
    float* out = (float*)d_out;
    if (ws_size >= WS_NEEDED) {
        unsigned short* CBF = (unsigned short*)d_ws;
        float* C2 = (float*)((char*)d_ws + CBF_BYTES);
        vq_prep<<<dim3(8, NBAND), dim3(256), 0, stream>>>(cb, CBF, C2);
        dim3 grid((TT + MT - 1) / MT, NBAND, 2);
        vq_main<<<grid, dim3(256), 0, stream>>>(x, cb, CBF, C2, out);
    } else {
        dim3 grid((TT + TN - 1) / TN, NBAND, 2);
        vq_fp32_kernel<<<grid, dim3(256), 0, stream>>>(x, cb, out);
    }
}

// Round 7
// 194.220 us; speedup vs baseline: 1.1137x; 1.0576x over previous
//
#include <hip/hip_runtime.h>

// VQ nearest-codebook, round 7: round-6 structure + XCD-pinned bands.
// 1D grid, swizzle: xcd = id&7, band = xcd + 8*((id>>3)%5) -> all 48 blocks of a
// band (and its prep blocks) run on ONE XCD; per-XCD fragment working set
// 10.5 MB -> 1.28 MB, L2-resident. Depth-1 async prefetch then covers L2 latency.
//
// x: (2, 40, 64, 1500) f32 ; cb: (40, 1024, 64) f32
// out[b,band,c,t] = cb[band, argmin_k ||x[b,band,:,t]-cb[band,k]||^2, c]

#define NBAND  40
#define CH     64
#define TT     1500
#define NCODE  1024
#define MT     64      // t-tile per block
#define NTILE  24      // ceil(1500/64)
#define PAD    68      // x staging row stride (ushorts)
#define THRESH 1e-3f   // rescue margin; bf16-split err bound ~2e-4

typedef short v8s __attribute__((ext_vector_type(8)));
typedef float v4f __attribute__((ext_vector_type(4)));

// ws: CBF fragments [band][group 0..31][plane 0..7][lane 0..63][8 ushorts]
//   plane = ni*2+ks (hi) / 4+ni*2+ks (lo); content = code g*32+ni*16+(lane&15),
//   c = ks*32+(lane>>4)*8 .. +8.  Then C2 float[40*1024].
#define CBF_USHORTS ((size_t)NBAND * 32 * 8 * 64 * 8)
#define CBF_BYTES   (CBF_USHORTS * 2)
#define WS_NEEDED   (CBF_BYTES + (size_t)NBAND * NCODE * 4)

__device__ __forceinline__ unsigned short f2bf(float f) {
    unsigned u = __float_as_uint(f);
    return (unsigned short)((u + 0x7FFFu + ((u >> 16) & 1u)) >> 16);   // RNE
}
__device__ __forceinline__ float bf2f(unsigned short h) {
    return __uint_as_float(((unsigned)h) << 16);
}
__device__ __forceinline__ unsigned ford(float f) {
    unsigned u = __float_as_uint(f);
    return (u & 0x80000000u) ? ~u : (u | 0x80000000u);
}
__device__ __forceinline__ unsigned long long packsk(float f, unsigned k) {
    return ((unsigned long long)ford(f) << 32) | (unsigned long long)k;
}
__device__ __forceinline__ float med3f(float a, float b, float c) {
#if __has_builtin(__builtin_amdgcn_fmed3f)
    return __builtin_amdgcn_fmed3f(a, b, c);
#else
    return fminf(fmaxf(a, b), c);
#endif
}

typedef __attribute__((address_space(1))) const unsigned char* gas_p;
typedef __attribute__((address_space(3))) unsigned char*       las_p;
__device__ __forceinline__ void async_ld16(const void* g, void* l) {
    __builtin_amdgcn_global_load_lds((gas_p)g, (las_p)l, 16, 0, 0);
}

// ---------------- prep: split + swizzle codebook into ws (XCD-pinned) ----------------
__global__ __launch_bounds__(256)
void vq_prep(const float* __restrict__ cb,
             unsigned short* __restrict__ CBF,
             float* __restrict__ C2) {
    // 320 blocks 1D: xcd = id&7, band = xcd + 8*((id>>3)%5), gchunk = (id>>3)/5
    const int id     = blockIdx.x;
    const int v      = id >> 3;
    const int band   = (id & 7) + 8 * (v % 5);
    const int gchunk = v / 5;                          // 0..7
    const int g      = gchunk * 4 + (threadIdx.x >> 6);
    const int lane   = threadIdx.x & 63;
    const int col    = lane & 15;
    const int quad   = lane >> 4;

    float sq[2] = {0.f, 0.f};
    #pragma unroll
    for (int l = 0; l < 4; ++l) {
        const int ni = l >> 1, ks = l & 1;
        const int code = g * 32 + ni * 16 + col;
        const int c0   = ks * 32 + quad * 8;
        const float* src = cb + ((size_t)(band * NCODE + code)) * CH + c0;
        const float4 v0 = *(const float4*)src;
        const float4 v1 = *(const float4*)(src + 4);
        const float vv[8] = {v0.x, v0.y, v0.z, v0.w, v1.x, v1.y, v1.z, v1.w};
        union { unsigned short u[8]; v8s v; } hh, ll;
        #pragma unroll
        for (int j = 0; j < 8; ++j) {
            const unsigned short h = f2bf(vv[j]);
            hh.u[j] = h;
            ll.u[j] = f2bf(vv[j] - bf2f(h));
            sq[ni] = fmaf(vv[j], vv[j], sq[ni]);
        }
        const size_t gb = (size_t)(band * 32 + g) * 8;
        *(v8s*)&CBF[(gb + l)     * 512 + lane * 8] = hh.v;
        *(v8s*)&CBF[(gb + 4 + l) * 512 + lane * 8] = ll.v;
    }
    #pragma unroll
    for (int ni = 0; ni < 2; ++ni) {
        sq[ni] += __shfl_xor(sq[ni], 16);
        sq[ni] += __shfl_xor(sq[ni], 32);
    }
    if (quad == 0) {
        C2[band * NCODE + g * 32 + col]      = sq[0];
        C2[band * NCODE + g * 32 + 16 + col] = sq[1];
    }
}

// ---------------- main ----------------
__global__ __launch_bounds__(256, 4)
void vq_main(const float* __restrict__ x,
             const float* __restrict__ cb,
             const unsigned short* __restrict__ CBF,
             const float* __restrict__ C2f,
             float* __restrict__ out) {
    // 32 KB region: [x-stage hi/lo 17.4K] -> [frag dbuf 2x16K] -> [reduce 24K / epi 17.2K]
    __shared__ alignas(16) unsigned char SMEM[32768];
    __shared__ float c2_s[NCODE];                 // 4 KB
    __shared__ unsigned long long best_s[MT];     // 512 B
    __shared__ unsigned amb_s[2];
    __shared__ float xrow_s[CH];

    // 1920 blocks 1D, XCD-pinned band
    const int id    = blockIdx.x;
    const int v     = id >> 3;
    const int band  = (id & 7) + 8 * (v % 5);
    const int tb    = v / 5;                 // 0..47
    const int tile  = tb % NTILE;
    const int batch = tb / NTILE;
    const int t0    = tile * MT;

    const int tid   = threadIdx.x;
    const int wave  = tid >> 6;
    const int lane  = tid & 63;
    const int quad  = lane >> 4;
    const int col   = lane & 15;
    const int thalf = wave & 1;    // t rows [32*thalf, +32)
    const int khalf = wave >> 1;   // codes [512*khalf, +512)

    if (tid < 2) amb_s[tid] = 0u;
    {
        const float* src = C2f + band * NCODE;
        #pragma unroll
        for (int i = 0; i < 4; ++i) c2_s[tid + 256 * i] = src[tid + 256 * i];
    }
    // stage x tile as bf16 hi/lo, [t][c] padded rows (MT=64)
    {
        unsigned short* XH_s = (unsigned short*)SMEM;
        unsigned short* XL_s = XH_s + MT * PAD;
        const int c = tid & 63;
        const int g = tid >> 6;
        const float* src = x + ((size_t)(batch * NBAND + band) * CH + c) * TT + t0;
        #pragma unroll
        for (int i = 0; i < 4; ++i) {
            const int t = (g + 4 * i) * 4;
            float4 v4 = make_float4(0.f, 0.f, 0.f, 0.f);
            if (t0 + t + 3 < TT) v4 = *(const float4*)(src + t);   // TT%4==0
            const float vv[4] = {v4.x, v4.y, v4.z, v4.w};
            #pragma unroll
            for (int j = 0; j < 4; ++j) {
                const unsigned short h = f2bf(vv[j]);
                XH_s[(t + j) * PAD + c] = h;
                XL_s[(t + j) * PAD + c] = f2bf(vv[j] - bf2f(h));
            }
        }
    }
    __syncthreads();

    // A fragments register-resident: rows 32*thalf + mi*16 + col
    v8s ah[2][2], al[2][2];
    {
        unsigned short* XH_s = (unsigned short*)SMEM;
        unsigned short* XL_s = XH_s + MT * PAD;
        #pragma unroll
        for (int mi = 0; mi < 2; ++mi)
            #pragma unroll
            for (int ks = 0; ks < 2; ++ks) {
                const int off = (thalf * 32 + mi * 16 + col) * PAD + ks * 32 + quad * 8;
                ah[mi][ks] = *(const v8s*)&XH_s[off];
                al[mi][ks] = *(const v8s*)&XL_s[off];
            }
    }
    __syncthreads();   // x-tile consumed; SMEM becomes the fragment double-buffer

    float m1[8], m2[8];
    int   id8[8];
    #pragma unroll
    for (int i = 0; i < 8; ++i) { m1[i] = 3.4028235e38f; m2[i] = 3.4028235e38f; id8[i] = 0x7fffffff; }

    // staging: wave w stages 4 planes of its k-half's group for round r
    unsigned short* LBUF = (unsigned short*)SMEM;                 // [2][2][8][512]
    const unsigned short* cbase = CBF + (size_t)(band * 32) * 4096 + (size_t)lane * 8;
    const int pbase = thalf * 4;   // local planes staged by this wave

    auto stage_round = [&](int r, int b) {
        const int group = khalf * 16 + r;
        #pragma unroll
        for (int i = 0; i < 4; ++i) {
            const int p = pbase + i;
            async_ld16(cbase + (size_t)group * 4096 + p * 512,
                       LBUF + (size_t)b * 8192 + khalf * 4096 + p * 512);  // HW adds lane*16B
        }
    };

    stage_round(0, 0);

    for (int r = 0; r < 16; ++r) {
        __syncthreads();                       // own async loads drained -> buf[r&1] complete
        if (r + 1 < 16) stage_round(r + 1, (r + 1) & 1);

        const unsigned short* lb = LBUF + (size_t)(r & 1) * 8192 + khalf * 4096 + lane * 8;
        v4f acc[2][2];
        #pragma unroll
        for (int mi = 0; mi < 2; ++mi)
            #pragma unroll
            for (int ni = 0; ni < 2; ++ni) acc[mi][ni] = (v4f){0.f, 0.f, 0.f, 0.f};

        #pragma unroll
        for (int ks = 0; ks < 2; ++ks) {
            const v8s bh0 = *(const v8s*)(lb + (0 + ks) * 512);
            const v8s bh1 = *(const v8s*)(lb + (2 + ks) * 512);
            const v8s bl0 = *(const v8s*)(lb + (4 + ks) * 512);
            const v8s bl1 = *(const v8s*)(lb + (6 + ks) * 512);
            #pragma unroll
            for (int mi = 0; mi < 2; ++mi) {
                acc[mi][0] = __builtin_amdgcn_mfma_f32_16x16x32_bf16(ah[mi][ks], bh0, acc[mi][0], 0, 0, 0);
                acc[mi][1] = __builtin_amdgcn_mfma_f32_16x16x32_bf16(ah[mi][ks], bh1, acc[mi][1], 0, 0, 0);
            }
            #pragma unroll
            for (int mi = 0; mi < 2; ++mi) {
                acc[mi][0] = __builtin_amdgcn_mfma_f32_16x16x32_bf16(ah[mi][ks], bl0, acc[mi][0], 0, 0, 0);
                acc[mi][1] = __builtin_amdgcn_mfma_f32_16x16x32_bf16(ah[mi][ks], bl1, acc[mi][1], 0, 0, 0);
            }
            #pragma unroll
            for (int mi = 0; mi < 2; ++mi) {
                acc[mi][0] = __builtin_amdgcn_mfma_f32_16x16x32_bf16(al[mi][ks], bh0, acc[mi][0], 0, 0, 0);
                acc[mi][1] = __builtin_amdgcn_mfma_f32_16x16x32_bf16(al[mi][ks], bh1, acc[mi][1], 0, 0, 0);
            }
        }
        // (m1, idx, m2): k strictly ascending per slot -> strict '<' keeps first-min
        #pragma unroll
        for (int ni = 0; ni < 2; ++ni) {
            const int   kg  = khalf * 512 + r * 32 + ni * 16 + col;
            const float c2v = c2_s[kg];
            #pragma unroll
            for (int mi = 0; mi < 2; ++mi)
                #pragma unroll
                for (int rr = 0; rr < 4; ++rr) {
                    const int j = mi * 4 + rr;
                    const float s = fmaf(-2.f, acc[mi][ni][rr], c2v);
                    m2[j] = med3f(s, m1[j], m2[j]);   // new second-min (m1<=m2 invariant)
                    const bool lt = s < m1[j];
                    m1[j]  = lt ? s : m1[j];
                    id8[j] = lt ? kg : id8[j];
                }
        }
    }
    __syncthreads();

    // cross-(col,khalf) reduction: 32 partials per t (alias SMEM)
    float* RM1 = (float*)SMEM;            // [MT][32]
    float* RM2 = RM1 + MT * 32;           // [MT][32]
    int*   RI  = (int*)(RM2 + MT * 32);   // [MT][32]
    #pragma unroll
    for (int j = 0; j < 8; ++j) {
        const int t    = thalf * 32 + (j >> 2) * 16 + quad * 4 + (j & 3);
        const int slot = khalf * 16 + col;
        RM1[t * 32 + slot] = m1[j];
        RM2[t * 32 + slot] = m2[j];
        RI [t * 32 + slot] = id8[j];
    }
    __syncthreads();

    if (tid < MT) {
        const int t = tid;
        float M1 = RM1[t * 32], M2 = RM2[t * 32];
        int   I  = RI[t * 32];
        #pragma unroll 8
        for (int j = 1; j < 32; ++j) {
            const float a1 = RM1[t * 32 + j];
            const float a2 = RM2[t * 32 + j];
            const int   ai = RI [t * 32 + j];
            if (a1 < M1 || (a1 == M1 && ai < I)) { M2 = fminf(M2, M1); M1 = a1; I = ai; }
            else                                  { M2 = fminf(M2, a1); }
            M2 = fminf(M2, a2);
        }
        best_s[t] = packsk(M1, (unsigned)I);
        if ((M2 - M1) <= THRESH && t0 + t < TT)
            atomicOr(&amb_s[t >> 5], 1u << (t & 31));
    }
    __syncthreads();

    // exact fp32 rescue for near-ties (rare)
    for (int t = 0; t < MT; ++t) {
        if ((amb_s[t >> 5] >> (t & 31)) & 1u) {
            if (tid < CH) xrow_s[tid] = x[((size_t)(batch * NBAND + band) * CH + tid) * TT + t0 + t];
            if (tid == CH) best_s[t] = ~0ULL;
            __syncthreads();
            #pragma unroll
            for (int i = 0; i < 4; ++i) {
                const int k = tid * 4 + i;
                const float* crow = cb + ((size_t)(band * NCODE + k)) * CH;
                float dot = 0.f, c2e = 0.f;
                #pragma unroll 8
                for (int c = 0; c < CH; ++c) {
                    const float cv = crow[c];
                    dot = fmaf(cv, xrow_s[c], dot);
                    c2e = fmaf(cv, cv, c2e);
                }
                atomicMin(&best_s[t], packsk(fmaf(-2.f, dot, c2e), (unsigned)k));
            }
            __syncthreads();
        }
    }
    __syncthreads();

    // epilogue via LDS: rows read coalesced (256B), stores coalesced along t
    {
        float* OT = (float*)SMEM;   // [MT][67] = 17152 B
        #pragma unroll
        for (int rr = 0; rr < MT; rr += 4) {
            const int row = rr + wave;
            const unsigned idx = (unsigned)(best_s[row] & 0xFFFFFFFFull) & (NCODE - 1);
            OT[row * 67 + lane] = cb[((size_t)(band * NCODE + idx)) * CH + lane];
        }
        __syncthreads();
        const int tloc = tid & 63;
        const int cq   = tid >> 6;   // 0..3
        if (t0 + tloc < TT) {
            float* ob = out + ((size_t)(batch * NBAND + band) * CH) * TT + t0 + tloc;
            #pragma unroll
            for (int i = 0; i < 16; ++i) {
                const int c = cq * 16 + i;
                ob[(size_t)c * TT] = OT[tloc * 67 + c];
            }
        }
    }
}

// ---------------- fallback: round-1 fp32 kernel (proven, ~290 us) ----------------
#define TN 128
#define KC 128
__global__ __launch_bounds__(256, 2)
void vq_fp32_kernel(const float* __restrict__ x,
                    const float* __restrict__ cb,
                    float* __restrict__ out) {
    __shared__ float XT_s[CH * TN];
    __shared__ float CBT_s[CH * KC];
    __shared__ float c2part[256];
    const int tile = blockIdx.x, band = blockIdx.y, batch = blockIdx.z;
    const int t0 = tile * TN;
    const int tid = threadIdx.x;
    const int tx = tid & 15, ty = tid >> 4;
    {
        const int c = tid >> 2, q = tid & 3;
        const float* src = x + ((size_t)(batch * NBAND + band) * CH + c) * TT + t0;
        #pragma unroll
        for (int i = 0; i < 8; ++i) {
            const int t = q * 32 + i * 4;
            float4 v = make_float4(0.f, 0.f, 0.f, 0.f);
            if (t0 + t < TT) v = *(const float4*)(src + t);
            *(float4*)&XT_s[c * TN + t] = v;
        }
    }
    float vmin[8]; int vidx[8];
    #pragma unroll
    for (int i = 0; i < 8; ++i) { vmin[i] = 3.4e38f; vidx[i] = 0x7fffffff; }
    for (int kc = 0; kc < NCODE; kc += KC) {
        __syncthreads();
        {
            const int k = tid >> 1, ch0 = (tid & 1) * 32;
            const float* src = cb + ((size_t)(band * NCODE + kc + k)) * CH + ch0;
            float s = 0.f;
            #pragma unroll
            for (int i = 0; i < 8; ++i) {
                const float4 v = *(const float4*)(src + i * 4);
                const int c0 = ch0 + i * 4;
                CBT_s[(c0 + 0) * KC + k] = v.x; CBT_s[(c0 + 1) * KC + k] = v.y;
                CBT_s[(c0 + 2) * KC + k] = v.z; CBT_s[(c0 + 3) * KC + k] = v.w;
                s = fmaf(v.x, v.x, s); s = fmaf(v.y, v.y, s);
                s = fmaf(v.z, v.z, s); s = fmaf(v.w, v.w, s);
            }
            c2part[tid] = s;
        }
        __syncthreads();
        float acc[8][8];
        #pragma unroll
        for (int ii = 0; ii < 8; ++ii)
            #pragma unroll
            for (int jj = 0; jj < 8; ++jj) acc[ii][jj] = 0.f;
        #pragma unroll 4
        for (int c = 0; c < CH; ++c) {
            const float4 xa0 = *(const float4*)&XT_s[c * TN + tx * 4];
            const float4 xa1 = *(const float4*)&XT_s[c * TN + 64 + tx * 4];
            const float4 cv0 = *(const float4*)&CBT_s[c * KC + ty * 4];
            const float4 cv1 = *(const float4*)&CBT_s[c * KC + 64 + ty * 4];
            const float xa[8] = {xa0.x, xa0.y, xa0.z, xa0.w, xa1.x, xa1.y, xa1.z, xa1.w};
            const float cv[8] = {cv0.x, cv0.y, cv0.z, cv0.w, cv1.x, cv1.y, cv1.z, cv1.w};
            #pragma unroll
            for (int ii = 0; ii < 8; ++ii)
                #pragma unroll
                for (int jj = 0; jj < 8; ++jj) acc[ii][jj] = fmaf(xa[ii], cv[jj], acc[ii][jj]);
        }
        #pragma unroll
        for (int jj = 0; jj < 8; ++jj) {
            const int kl = (jj < 4) ? (ty * 4 + jj) : (64 + ty * 4 + (jj - 4));
            const float c2v = c2part[2 * kl] + c2part[2 * kl + 1];
            const int kglob = kc + kl;
            #pragma unroll
            for (int ii = 0; ii < 8; ++ii) {
                const float score = fmaf(-2.f, acc[ii][jj], c2v);
                if (score < vmin[ii]) { vmin[ii] = score; vidx[ii] = kglob; }
            }
        }
    }
    __syncthreads();
    float* redv = XT_s;
    int* redi = (int*)(XT_s + TN * 16);
    int* idxs = (int*)(XT_s + TN * 32);
    #pragma unroll
    for (int ii = 0; ii < 8; ++ii) {
        const int t = (ii < 4) ? (tx * 4 + ii) : (64 + tx * 4 + (ii - 4));
        redv[t * 16 + ty] = vmin[ii];
        redi[t * 16 + ty] = vidx[ii];
    }
    __syncthreads();
    if (tid < TN) {
        float bv = redv[tid * 16]; int bi = redi[tid * 16];
        #pragma unroll
        for (int j = 1; j < 16; ++j) {
            const float v = redv[tid * 16 + j]; const int id = redi[tid * 16 + j];
            if (v < bv || (v == bv && id < bi)) { bv = v; bi = id; }
        }
        idxs[tid] = bi;
    }
    __syncthreads();
    {
        const int tloc = tid & 127, chalf = tid >> 7;
        if (t0 + tloc < TT) {
            const int idx = idxs[tloc];
            const float* crow = cb + ((size_t)(band * NCODE + idx)) * CH;
            float* ob = out + ((size_t)(batch * NBAND + band) * CH) * TT + t0 + tloc;
            #pragma unroll
            for (int i = 0; i < 32; ++i) {
                const int c = chalf * 32 + i;
                ob[(size_t)c * TT] = crow[c];
            }
        }
    }
}

extern "C" void kernel_launch(void* const* d_in, const int* in_sizes, int n_in,
                              void* d_out, int out_size, void* d_ws, size_t ws_size,
                              hipStream_t stream) {
    const float* x  = (const float*)d_in[0];
    const float* cb = (const float*)d_in[1];
    float* out = (float*)d_out;
    if (ws_size >= WS_NEEDED) {
        unsigned short* CBF = (unsigned short*)d_ws;
        float* C2 = (float*)((char*)d_ws + CBF_BYTES);
        vq_prep<<<dim3(8 * 5 * 8), dim3(256), 0, stream>>>(cb, CBF, C2);
        vq_main<<<dim3(8 * 5 * NTILE * 2), dim3(256), 0, stream>>>(x, cb, CBF, C2, out);
    } else {
        dim3 grid((TT + TN - 1) / TN, NBAND, 2);
        vq_fp32_kernel<<<grid, dim3(256), 0, stream>>>(x, cb, out);
    }
}